// Round 10
// baseline (6350.114 us; speedup 1.0000x reference)
//
#include <hip/hip_runtime.h>
#include <hip/hip_bf16.h>

// GRU B=128, S=512, H=1024 — persistent kernel, r4-proven IC (sc0 sc1) flag
// protocol with direct IC->register fragment loads (no LDS staging, no
// syncthreads in loop, producer-only drains, shadow out-stores).
// 8 independent groups x 32 WGs (g = wg&7); group owns 16 batch rows; WG owns
// 32 cols. Single pxi / av buffer per group (32KB each) — overwrite safety by
// transitive dependency: pxi(t+1) publish <= av(t) all-visible <= every WG's
// r+z pxi-loads done (zl flags + partial flags); av(t+1) publish <= pxi(t+1)
// all-visible <= every WG's h av-loads done (B-partial flags).
// Waves (ntX = wid&1): phase A: wid<4 r-GEMM (Ww, kh=(wid>>1)&1), wid>=4
// z-GEMM (Uw); finalizers 0,1 -> av publish (own slot), 4,5 -> zz regs.
// Phase B: h-GEMM (Vw, kq=wid>>1); finalizers 4,5: gate, p_lds, pxi publish
// (own slot), out in shadow. Pollers: wave0 (pxi slots), wave4 (av slots);
// others spin LDS flags. 64 slots x 16B per group per buffer, one 64-lane load.

#define Ss 512
#define Hh 1024
#define NWG 256
#define NTHR 512

typedef __bf16 bf16x8 __attribute__((ext_vector_type(8)));
typedef float f32x4 __attribute__((ext_vector_type(4)));
typedef int   i32x4 __attribute__((ext_vector_type(4)));

__device__ __forceinline__ float sigmoid_fast(float x) { return 1.f / (1.f + __expf(-x)); }
__device__ __forceinline__ float tanh_fast(float x) { return 2.f / (1.f + __expf(-2.f * x)) - 1.f; }

__device__ __forceinline__ unsigned lds_ld(const unsigned* p) {
    return __hip_atomic_load(p, __ATOMIC_RELAXED, __HIP_MEMORY_SCOPE_WORKGROUP);
}
__device__ __forceinline__ void lds_st(unsigned* p, unsigned v) {
    __hip_atomic_store(p, v, __ATOMIC_RELAXED, __HIP_MEMORY_SCOPE_WORKGROUP);
}
__device__ __forceinline__ void spin_ge(const unsigned* p, unsigned T) {
    while (lds_ld(p) < T) { }
    __builtin_amdgcn_sched_barrier(0);
}
__device__ __forceinline__ void ic_store64(char* p, unsigned long long v) {
    asm volatile("global_store_dwordx2 %0, %1, off sc0 sc1" :: "v"(p), "v"(v) : "memory");
}
__device__ __forceinline__ void ic_store32(char* p, unsigned v) {
    asm volatile("global_store_dword %0, %1, off sc0 sc1" :: "v"(p), "v"(v) : "memory");
}

// poll 64 slots (16B stride) until all >= tgt; one 64-lane load per iteration
__device__ __forceinline__ void pollslots(const char* base, int lane, unsigned tgt) {
    const char* p = base + lane * 16;
    unsigned v;
    do {
        asm volatile("global_load_dword %0, %1, off sc0 sc1\n\ts_waitcnt vmcnt(0)"
                     : "=v"(v) : "v"(p) : "memory");
    } while (__any((int)(v < tgt)));
    __builtin_amdgcn_sched_barrier(0);
}

__device__ __forceinline__ void load16(const char* a, i32x4 (&fr)[16]) {
    asm volatile(
        "global_load_dwordx4 %0, %16, off offset:0 sc0 sc1\n\t"
        "global_load_dwordx4 %1, %16, off offset:64 sc0 sc1\n\t"
        "global_load_dwordx4 %2, %16, off offset:128 sc0 sc1\n\t"
        "global_load_dwordx4 %3, %16, off offset:192 sc0 sc1\n\t"
        "global_load_dwordx4 %4, %16, off offset:256 sc0 sc1\n\t"
        "global_load_dwordx4 %5, %16, off offset:320 sc0 sc1\n\t"
        "global_load_dwordx4 %6, %16, off offset:384 sc0 sc1\n\t"
        "global_load_dwordx4 %7, %16, off offset:448 sc0 sc1\n\t"
        "global_load_dwordx4 %8, %16, off offset:512 sc0 sc1\n\t"
        "global_load_dwordx4 %9, %16, off offset:576 sc0 sc1\n\t"
        "global_load_dwordx4 %10, %16, off offset:640 sc0 sc1\n\t"
        "global_load_dwordx4 %11, %16, off offset:704 sc0 sc1\n\t"
        "global_load_dwordx4 %12, %16, off offset:768 sc0 sc1\n\t"
        "global_load_dwordx4 %13, %16, off offset:832 sc0 sc1\n\t"
        "global_load_dwordx4 %14, %16, off offset:896 sc0 sc1\n\t"
        "global_load_dwordx4 %15, %16, off offset:960 sc0 sc1\n\t"
        "s_waitcnt vmcnt(0)"
        : "=&v"(fr[0]), "=&v"(fr[1]), "=&v"(fr[2]), "=&v"(fr[3]),
          "=&v"(fr[4]), "=&v"(fr[5]), "=&v"(fr[6]), "=&v"(fr[7]),
          "=&v"(fr[8]), "=&v"(fr[9]), "=&v"(fr[10]), "=&v"(fr[11]),
          "=&v"(fr[12]), "=&v"(fr[13]), "=&v"(fr[14]), "=&v"(fr[15])
        : "v"(a) : "memory");
    __builtin_amdgcn_sched_barrier(0);
}
__device__ __forceinline__ void load8(const char* a, i32x4 (&fr)[8]) {
    asm volatile(
        "global_load_dwordx4 %0, %8, off offset:0 sc0 sc1\n\t"
        "global_load_dwordx4 %1, %8, off offset:64 sc0 sc1\n\t"
        "global_load_dwordx4 %2, %8, off offset:128 sc0 sc1\n\t"
        "global_load_dwordx4 %3, %8, off offset:192 sc0 sc1\n\t"
        "global_load_dwordx4 %4, %8, off offset:256 sc0 sc1\n\t"
        "global_load_dwordx4 %5, %8, off offset:320 sc0 sc1\n\t"
        "global_load_dwordx4 %6, %8, off offset:384 sc0 sc1\n\t"
        "global_load_dwordx4 %7, %8, off offset:448 sc0 sc1\n\t"
        "s_waitcnt vmcnt(0)"
        : "=&v"(fr[0]), "=&v"(fr[1]), "=&v"(fr[2]), "=&v"(fr[3]),
          "=&v"(fr[4]), "=&v"(fr[5]), "=&v"(fr[6]), "=&v"(fr[7])
        : "v"(a) : "memory");
    __builtin_amdgcn_sched_barrier(0);
}

__global__ __launch_bounds__(NTHR, 1) void gru_v10(
    const float* __restrict__ emb, const float* __restrict__ Ww,
    const float* __restrict__ Wb, const float* __restrict__ Uw,
    const float* __restrict__ Ub, const float* __restrict__ Vw,
    const float* __restrict__ Vb,
    char* __restrict__ xbuf, char* __restrict__ abuf,
    char* __restrict__ slotbuf, float* __restrict__ out)
{
    __shared__ f32x4   scA[4][64];
    __shared__ f32x4   scB[8][64];
    __shared__ float    p_lds[16][34];
    __shared__ __bf16   bpack[8][16][20];
    __shared__ float    fpack[2][16][20];
    __shared__ unsigned flags[32][16];
    // flags[0..7]: A partials (by wid; 2,3,6,7 write). flags[8..15]: B partials
    // (0,1,2,3,6,7 write). flags[16..19]: z-load-done (wid-4). [20]=fA, [21]=fB.

    const int tid = threadIdx.x, lane = tid & 63, wid = tid >> 6;
    const int la = lane & 15, lb = lane >> 4;
    const int wg = blockIdx.x, g = wg & 7, lw = wg >> 3;
    const int rbase = g * 16, n0 = lw * 32;
    const int ntA = wid & 1, khA = (wid >> 1) & 1;
    const int kqB = wid >> 1;
    const int prow = lane >> 2, pcg = lane & 3;
    char* pxiG = xbuf + g * 32768;
    char* avG  = abuf + g * 32768;
    char* pxiSlots = slotbuf + g * 4096;
    char* avSlots  = slotbuf + 32768 + g * 4096;

    // ---- weights -> registers (B-frag layout verified r3/r4/r9) ----
    bf16x8 WA[16], VB[8];
    {
        const float* w1 = (wid < 4) ? Ww : Uw;
        const float* s1 = w1 + (size_t)(n0 + ntA * 16 + la) * Hh + khA * 512;
#pragma unroll
        for (int i = 0; i < 16; ++i) {
            bf16x8 v;
#pragma unroll
            for (int j = 0; j < 8; ++j) v[j] = (__bf16)s1[i * 32 + lb * 8 + j];
            WA[i] = v;
        }
        const float* s2 = Vw + (size_t)(n0 + ntA * 16 + la) * Hh + kqB * 256;
#pragma unroll
        for (int i = 0; i < 8; ++i) {
            bf16x8 v;
#pragma unroll
            for (int j = 0; j < 8; ++j) v[j] = (__bf16)s2[i * 32 + lb * 8 + j];
            VB[i] = v;
        }
    }
    float bias1 = 0.f, bias2 = 0.f;
    if      (wid == 0) bias1 = Wb[n0 + la];
    else if (wid == 1) bias1 = Wb[n0 + 16 + la];
    else if (wid == 4) { bias1 = Ub[n0 + la];      bias2 = Vb[n0 + la]; }
    else if (wid == 5) { bias1 = Ub[n0 + 16 + la]; bias2 = Vb[n0 + 16 + la]; }

    // ---- LDS init + initial pxi(0) publish ----
    for (int i = tid; i < 16 * 34; i += NTHR) ((float*)p_lds)[i] = 0.f;
    if (tid < 512) (&flags[0][0])[tid] = 0u;
    __syncthreads();
    f32x4 pv = {0.f, 0.f, 0.f, 0.f};
    if (wid == 4 || wid == 5) {
        const int nt = wid - 4, jc = n0 + nt * 16 + la;
#pragma unroll
        for (int r = 0; r < 4; ++r)
            bpack[wid][lb * 4 + r][la] =
                (__bf16)emb[(size_t)(rbase + lb * 4 + r) * Ss * Hh + jc];
        asm volatile("s_waitcnt lgkmcnt(0)" ::: "memory");
        __builtin_amdgcn_sched_barrier(0);
        unsigned long long d = *(const unsigned long long*)&bpack[wid][prow][pcg * 4];
        ic_store64(pxiG + prow * 2048 + (n0 + nt * 16 + pcg * 4) * 2, d);
        asm volatile("s_waitcnt vmcnt(0)" ::: "memory");
        if (lane == 0) ic_store32(pxiSlots + (2 * lw + nt) * 16, 1u);
    }

    const char* aAddrA = pxiG + la * 2048 + khA * 1024 + lb * 16;
    const char* aAddrB = avG  + la * 2048 + kqB * 512  + lb * 16;
    const int scAi = ((wid >> 2) << 1) | (wid & 1);   // partner-pair slot

    for (int t = 0; t < Ss; ++t) {
        const unsigned T = (unsigned)(t + 1);
        // predictable epilogue loads overlap the coming polls
        f32x4 embc = {0.f,0.f,0.f,0.f}, embn = embc;
        if (wid < 2) {
#pragma unroll
            for (int r = 0; r < 4; ++r)
                embc[r] = emb[((size_t)(rbase + lb * 4 + r) * Ss + t) * Hh + (n0 + ntA * 16 + la)];
        } else if ((wid == 4 || wid == 5) && t + 1 < Ss) {
#pragma unroll
            for (int r = 0; r < 4; ++r)
                embn[r] = emb[((size_t)(rbase + lb * 4 + r) * Ss + (t + 1)) * Hh + (n0 + (wid - 4) * 16 + la)];
        }

        // ---- phase A: pxi(t) ready -> direct frag loads -> r/z GEMM ----
        if (wid == 0) { pollslots(pxiSlots, lane, T); lds_st(&flags[20][0], T); }
        else          spin_ge(&flags[20][0], T);
        i32x4 fr[16];
        load16(aAddrA, fr);
        if (wid >= 4) lds_st(&flags[16 + wid - 4][0], T);    // z pxi-loads done
        f32x4 a0 = {0.f,0.f,0.f,0.f}, a1 = a0;
#pragma unroll
        for (int i = 0; i < 8; ++i) {
            a0 = __builtin_amdgcn_mfma_f32_16x16x32_bf16(
                     __builtin_bit_cast(bf16x8, fr[2 * i]),     WA[2 * i],     a0, 0, 0, 0);
            a1 = __builtin_amdgcn_mfma_f32_16x16x32_bf16(
                     __builtin_bit_cast(bf16x8, fr[2 * i + 1]), WA[2 * i + 1], a1, 0, 0, 0);
        }
        f32x4 acc = a0 + a1;
        f32x4 zz = {0.f,0.f,0.f,0.f};
        if (khA == 1) {                                      // partner partial
            scA[scAi][lane] = acc;
            asm volatile("s_waitcnt lgkmcnt(0)" ::: "memory");
            lds_st(&flags[wid][0], T);
        } else {
            spin_ge(&flags[wid + 2][0], T);
            acc += scA[scAi][lane];
            if (wid < 2) {                                   // r finalize -> av
                spin_ge(&flags[16][0], T); spin_ge(&flags[17][0], T);
                spin_ge(&flags[18][0], T); spin_ge(&flags[19][0], T);
#pragma unroll
                for (int r = 0; r < 4; ++r) {
                    float rg = sigmoid_fast(acc[r] + bias1);
                    float pc = p_lds[lb * 4 + r][ntA * 16 + la];
                    bpack[wid][lb * 4 + r][la] = (__bf16)(rg * pc + embc[r]);
                }
                asm volatile("s_waitcnt lgkmcnt(0)" ::: "memory");
                __builtin_amdgcn_sched_barrier(0);
                unsigned long long d = *(const unsigned long long*)&bpack[wid][prow][pcg * 4];
                ic_store64(avG + prow * 2048 + (n0 + ntA * 16 + pcg * 4) * 2, d);
                asm volatile("s_waitcnt vmcnt(0)" ::: "memory");
                if (lane == 0) ic_store32(avSlots + (2 * lw + wid) * 16, T);
            } else {                                         // z finalize -> regs
#pragma unroll
                for (int r = 0; r < 4; ++r) zz[r] = sigmoid_fast(acc[r] + bias1);
            }
        }

        // ---- phase B: av(t) ready -> direct frag loads -> h GEMM -> gate ----
        if (wid == 4) { pollslots(avSlots, lane, T); lds_st(&flags[21][0], T); }
        else          spin_ge(&flags[21][0], T);
        i32x4 fb[8];
        load8(aAddrB, fb);
        f32x4 h0 = {0.f,0.f,0.f,0.f}, h1 = h0;
#pragma unroll
        for (int i = 0; i < 4; ++i) {
            h0 = __builtin_amdgcn_mfma_f32_16x16x32_bf16(
                     __builtin_bit_cast(bf16x8, fb[2 * i]),     VB[2 * i],     h0, 0, 0, 0);
            h1 = __builtin_amdgcn_mfma_f32_16x16x32_bf16(
                     __builtin_bit_cast(bf16x8, fb[2 * i + 1]), VB[2 * i + 1], h1, 0, 0, 0);
        }
        f32x4 hacc = h0 + h1;
        if (wid == 4 || wid == 5) {                          // gate finalize
            const int o = wid & 1;
            spin_ge(&flags[8 + o][0], T);
            spin_ge(&flags[10 + o][0], T);
            spin_ge(&flags[14 + o][0], T);
            hacc += scB[o][lane] + scB[2 + o][lane] + scB[6 + o][lane];
            f32x4 pn;
#pragma unroll
            for (int r = 0; r < 4; ++r) {
                float h = tanh_fast(hacc[r] + bias2);
                pn[r] = (1.f - zz[r]) * pv[r] + zz[r] * h;
                pv[r] = pn[r];
                p_lds[lb * 4 + r][o * 16 + la] = pn[r];
            }
            if (t + 1 < Ss) {
#pragma unroll
                for (int r = 0; r < 4; ++r)
                    bpack[wid][lb * 4 + r][la] = (__bf16)(pn[r] + embn[r]);
                asm volatile("s_waitcnt lgkmcnt(0)" ::: "memory");   // covers p_lds too
                __builtin_amdgcn_sched_barrier(0);
                unsigned long long d = *(const unsigned long long*)&bpack[wid][prow][pcg * 4];
                ic_store64(pxiG + prow * 2048 + (n0 + o * 16 + pcg * 4) * 2, d);
                asm volatile("s_waitcnt vmcnt(0)" ::: "memory");
                if (lane == 0) ic_store32(pxiSlots + (2 * lw + o) * 16, T + 1);
            }
            // shadow: out store (no reader, off critical path)
#pragma unroll
            for (int r = 0; r < 4; ++r) fpack[o][lb * 4 + r][la] = pn[r];
            asm volatile("s_waitcnt lgkmcnt(0)" ::: "memory");
            __builtin_amdgcn_sched_barrier(0);
            f32x4 ov = *(const f32x4*)&fpack[o][prow][pcg * 4];
            *(f32x4*)(out + ((size_t)(rbase + prow) * Ss + t) * Hh + n0 + o * 16 + pcg * 4) = ov;
        } else {                                             // h partial
            scB[wid][lane] = hacc;
            asm volatile("s_waitcnt lgkmcnt(0)" ::: "memory");
            lds_st(&flags[8 + wid][0], T);
        }
    }
}

// ---- launch -----------------------------------------------------------------

extern "C" void kernel_launch(void* const* d_in, const int* in_sizes, int n_in,
                              void* d_out, int out_size, void* d_ws, size_t ws_size,
                              hipStream_t stream) {
    const float* emb = (const float*)d_in[0];
    const float* Ww  = (const float*)d_in[1];
    const float* Wb  = (const float*)d_in[2];
    const float* Uw  = (const float*)d_in[3];
    const float* Ub  = (const float*)d_in[4];
    const float* Vw  = (const float*)d_in[5];
    const float* Vb  = (const float*)d_in[6];
    float* out = (float*)d_out;

    char* xbuf    = (char*)d_ws;                  // 256 KB (8 groups x 32 KB)
    char* abuf    = (char*)d_ws + (256 << 10);    // 256 KB
    char* slotbuf = (char*)d_ws + (512 << 10);    // 64 KB (2 arrays x 8 x 4 KB)

    hipMemsetAsync(slotbuf, 0, 65536, stream);

    void* args[] = {(void*)&emb, (void*)&Ww, (void*)&Wb, (void*)&Uw, (void*)&Ub,
                    (void*)&Vw, (void*)&Vb, (void*)&xbuf, (void*)&abuf,
                    (void*)&slotbuf, (void*)&out};
    hipError_t e = hipLaunchCooperativeKernel(
        reinterpret_cast<const void*>(gru_v10), dim3(NWG), dim3(NTHR),
        args, 0, stream);
    if (e != hipSuccess) {
        gru_v10<<<dim3(NWG), dim3(NTHR), 0, stream>>>(
            emb, Ww, Wb, Uw, Ub, Vw, Vb, xbuf, abuf, slotbuf, out);
    }
}